// Round 1
// baseline (2080.807 us; speedup 1.0000x reference)
//
#include <hip/hip_runtime.h>

#define NOBS 64
#define NH1  20
#define NH2  50
#define NACT 16

// sigmoid/tanh via native exp (v_exp_f32) + rcp (v_rcp_f32).
// abs error ~1e-6 -- far below any fp32 validation threshold.
__device__ __forceinline__ float fsigmoid(float v) {
    return __builtin_amdgcn_rcpf(1.0f + __expf(-v));
}
__device__ __forceinline__ float ftanh(float v) {
    // tanh(x) = 1 - 2/(exp(2x)+1); exp overflow -> inf -> rcp -> 0 -> 1.0 (correct saturation)
    float e = __expf(2.0f * v);
    return 1.0f - 2.0f * __builtin_amdgcn_rcpf(e + 1.0f);
}

// One thread = one sample. All per-sample state in VGPRs with static indexing.
// Weight reads are wave-uniform (uniform pointer + uniform index) -> s_load path.
__global__ __launch_bounds__(256) void actor_kernel(
    const float* __restrict__ x,
    const float* __restrict__ hx,
    const float* __restrict__ cx,
    const float* __restrict__ fc1w, const float* __restrict__ fc1b,
    const float* __restrict__ fc2w, const float* __restrict__ fc2b,
    const float* __restrict__ wih,  const float* __restrict__ whh,
    const float* __restrict__ bih,  const float* __restrict__ bhh,
    const float* __restrict__ fc3w, const float* __restrict__ fc3b,
    float* __restrict__ outp, float* __restrict__ hxo, float* __restrict__ cxo,
    int B)
{
    const int t = blockIdx.x * blockDim.x + threadIdx.x;
    if (t >= B) return;

    // ---- load x[64]: 16 x dwordx4, every fetched line fully consumed by this thread
    float xv[NOBS];
    {
        const float4* xp = reinterpret_cast<const float4*>(x) + (size_t)t * (NOBS / 4);
        #pragma unroll
        for (int q = 0; q < NOBS / 4; ++q) {
            float4 v = xp[q];
            xv[4*q+0] = v.x; xv[4*q+1] = v.y; xv[4*q+2] = v.z; xv[4*q+3] = v.w;
        }
    }

    // ---- fc1 + relu (fully unrolled: h1[] must stay statically indexed)
    float h1[NH1];
    #pragma unroll
    for (int i = 0; i < NH1; ++i) {
        float a0 = fc1b[i], a1 = 0.f, a2 = 0.f, a3 = 0.f;
        #pragma unroll
        for (int k = 0; k < NOBS; k += 4) {
            a0 = fmaf(xv[k+0], fc1w[i*NOBS + k+0], a0);
            a1 = fmaf(xv[k+1], fc1w[i*NOBS + k+1], a1);
            a2 = fmaf(xv[k+2], fc1w[i*NOBS + k+2], a2);
            a3 = fmaf(xv[k+3], fc1w[i*NOBS + k+3], a3);
        }
        h1[i] = fmaxf((a0 + a1) + (a2 + a3), 0.f);
    }

    // ---- fc2 + relu (fully unrolled)
    float h2[NH2];
    #pragma unroll
    for (int j = 0; j < NH2; ++j) {
        float a0 = fc2b[j], a1 = 0.f;
        #pragma unroll
        for (int k = 0; k < NH1; k += 2) {
            a0 = fmaf(h1[k+0], fc2w[j*NH1 + k+0], a0);
            a1 = fmaf(h1[k+1], fc2w[j*NH1 + k+1], a1);
        }
        h2[j] = fmaxf(a0 + a1, 0.f);
    }

    // ---- load hx[50] (8B vector loads; row is 200B so 8B-aligned)
    float hxr[NH2];
    {
        const float2* hp = reinterpret_cast<const float2*>(hx + (size_t)t * NH2);
        #pragma unroll
        for (int q = 0; q < NH2 / 2; ++q) {
            float2 v = hp[q];
            hxr[2*q+0] = v.x; hxr[2*q+1] = v.y;
        }
    }

    // ---- LSTM cell, one hidden unit per j-iteration, fc3 fused in
    float outa[NACT];
    #pragma unroll
    for (int a = 0; a < NACT; ++a) outa[a] = fc3b[a];

    const float* cxrow = cx  + (size_t)t * NH2;
    float* hxorow      = hxo + (size_t)t * NH2;
    float* cxorow      = cxo + (size_t)t * NH2;

    #pragma unroll 1   // keep rolled: body is ~400 FMAs; full unroll would blow I-cache
    for (int j = 0; j < NH2; ++j) {
        const float* wi = wih + (size_t)(j          ) * NH2;
        const float* wf = wih + (size_t)(NH2   + j  ) * NH2;
        const float* wg = wih + (size_t)(2*NH2 + j  ) * NH2;
        const float* wo = wih + (size_t)(3*NH2 + j  ) * NH2;
        const float* ui = whh + (size_t)(j          ) * NH2;
        const float* uf = whh + (size_t)(NH2   + j  ) * NH2;
        const float* ug = whh + (size_t)(2*NH2 + j  ) * NH2;
        const float* uo = whh + (size_t)(3*NH2 + j  ) * NH2;

        float ai = bih[j]         + bhh[j];
        float af = bih[NH2 + j]   + bhh[NH2 + j];
        float ag = bih[2*NH2 + j] + bhh[2*NH2 + j];
        float ao = bih[3*NH2 + j] + bhh[3*NH2 + j];
        float bi = 0.f, bf = 0.f, bg = 0.f, bo = 0.f;  // 8 chains for ILP

        #pragma unroll
        for (int k = 0; k < NH2; ++k) {
            ai = fmaf(h2[k],  wi[k], ai);
            af = fmaf(h2[k],  wf[k], af);
            ag = fmaf(h2[k],  wg[k], ag);
            ao = fmaf(h2[k],  wo[k], ao);
            bi = fmaf(hxr[k], ui[k], bi);
            bf = fmaf(hxr[k], uf[k], bf);
            bg = fmaf(hxr[k], ug[k], bg);
            bo = fmaf(hxr[k], uo[k], bo);
        }

        float ig = fsigmoid(ai + bi);
        float fg = fsigmoid(af + bf);
        float gg = ftanh(ag + bg);
        float og = fsigmoid(ao + bo);

        float cn = fmaf(fg, cxrow[j], ig * gg);
        float tn = ftanh(cn);
        float hn = og * tn;

        cxorow[j] = cn;
        hxorow[j] = hn;

        #pragma unroll
        for (int a = 0; a < NACT; ++a)
            outa[a] = fmaf(hn, fc3w[a*NH2 + j], outa[a]);
    }

    // ---- out = tanh(fc3), vectorized store
    {
        float4* op = reinterpret_cast<float4*>(outp + (size_t)t * NACT);
        #pragma unroll
        for (int q = 0; q < NACT / 4; ++q) {
            float4 v;
            v.x = ftanh(outa[4*q+0]);
            v.y = ftanh(outa[4*q+1]);
            v.z = ftanh(outa[4*q+2]);
            v.w = ftanh(outa[4*q+3]);
            op[q] = v;
        }
    }
}

extern "C" void kernel_launch(void* const* d_in, const int* in_sizes, int n_in,
                              void* d_out, int out_size, void* d_ws, size_t ws_size,
                              hipStream_t stream) {
    const float* x    = (const float*)d_in[0];
    const float* hx   = (const float*)d_in[1];
    const float* cx   = (const float*)d_in[2];
    const float* fc1w = (const float*)d_in[3];
    const float* fc1b = (const float*)d_in[4];
    const float* fc2w = (const float*)d_in[5];
    const float* fc2b = (const float*)d_in[6];
    const float* wih  = (const float*)d_in[7];
    const float* whh  = (const float*)d_in[8];
    const float* bih  = (const float*)d_in[9];
    const float* bhh  = (const float*)d_in[10];
    const float* fc3w = (const float*)d_in[11];
    const float* fc3b = (const float*)d_in[12];

    const int B = in_sizes[0] / NOBS;   // 524288

    float* outp = (float*)d_out;
    float* hxo  = outp + (size_t)B * NACT;
    float* cxo  = hxo  + (size_t)B * NH2;

    const int block = 256;
    const int grid  = (B + block - 1) / block;
    hipLaunchKernelGGL(actor_kernel, dim3(grid), dim3(block), 0, stream,
                       x, hx, cx, fc1w, fc1b, fc2w, fc2b,
                       wih, whh, bih, bhh, fc3w, fc3b,
                       outp, hxo, cxo, B);
}

// Round 3
// 1607.500 us; speedup vs baseline: 1.2944x; 1.2944x over previous
//
#include <hip/hip_runtime.h>

#define NOBS 64
#define NH1  20
#define NH2  50
#define NACT 16

// sigmoid/tanh via native exp (v_exp_f32) + rcp (v_rcp_f32). abs err ~1e-6.
__device__ __forceinline__ float fsigmoid(float v) {
    return __builtin_amdgcn_rcpf(1.0f + __expf(-v));
}
__device__ __forceinline__ float ftanh(float v) {
    // tanh(x) = 1 - 2/(exp(2x)+1); exp overflow -> inf -> rcp -> 0 -> 1.0 (correct saturation)
    float e = __expf(2.0f * v);
    return 1.0f - 2.0f * __builtin_amdgcn_rcpf(e + 1.0f);
}

// ---------------------------------------------------------------------------
// Transpose-out: src[50][B] -> dst[t][50]. blockIdx.y selects (hT->hxo)/(cT->cxo).
// LDS tile padded to 53 (53 mod 32 = 21, coprime -> conflict-free write;
// stride-1 read).
// ---------------------------------------------------------------------------
__global__ __launch_bounds__(256) void transpose_out(
    const float* __restrict__ srcH, float* __restrict__ dstH,
    const float* __restrict__ srcC, float* __restrict__ dstC, int B)
{
    __shared__ float tile[256 * 53];
    const int tid = threadIdx.x;
    const int r0  = blockIdx.x * 256;
    const float* src = (blockIdx.y == 0) ? srcH : srcC;
    float*       dst = (blockIdx.y == 0) ? dstH : dstC;

    if (r0 + tid < B) {
        #pragma unroll
        for (int j = 0; j < NH2; ++j)
            tile[tid * 53 + j] = src[(size_t)j * B + r0 + tid];
    }
    __syncthreads();
    #pragma unroll
    for (int p = 0; p < NH2; ++p) {
        int n = p * 256 + tid;
        int r = n / NH2, c = n % NH2;
        if (r0 + r < B)
            dst[(size_t)r0 * NH2 + n] = tile[r * 53 + c];
    }
}

// ---------------------------------------------------------------------------
// Main kernel. One thread = one sample; per-sample state in VGPRs, statically
// indexed. cx is staged block-locally into LDS (contiguous 51.2 KB slab per
// block -> coalesced global read; in-loop read ctile[j][tid] lane-stride 4B,
// 2 lanes/bank = free). hn/cn written coalesced to column-major scratch.
// LDS 50*257*4 = 51.4 KB -> 3 blocks/CU = 12 waves/CU.
// ---------------------------------------------------------------------------
__global__ __launch_bounds__(256) void actor_kernel(
    const float* __restrict__ x,
    const float* __restrict__ hx,
    const float* __restrict__ cx,
    const float* __restrict__ fc1w, const float* __restrict__ fc1b,
    const float* __restrict__ fc2w, const float* __restrict__ fc2b,
    const float* __restrict__ wih,  const float* __restrict__ whh,
    const float* __restrict__ bih,  const float* __restrict__ bhh,
    const float* __restrict__ fc3w, const float* __restrict__ fc3b,
    float* __restrict__ outp,
    float* __restrict__ hT,          // out: hn, [50][B]
    float* __restrict__ cT,          // out: cn, [50][B]
    int B)
{
    __shared__ float ctile[NH2 * 257];   // [c][r], pad 257 (==1 mod 32)
    const int tid = threadIdx.x;
    const int r0  = blockIdx.x * 256;
    const int t   = r0 + tid;

    // ---- stage cx rows r0..r0+255 into ctile[c][r]; global read coalesced,
    //      LDS write lane-stride 257 -> bank stride 1 -> conflict-free
    {
        const float* cbase = cx + (size_t)r0 * NH2;
        #pragma unroll
        for (int p = 0; p < NH2; ++p) {
            int n = p * 256 + tid;           // 0..12799
            int r = n / NH2, c = n % NH2;
            if (r0 + r < B)
                ctile[c * 257 + r] = cbase[n];
        }
    }
    __syncthreads();

    if (t >= B) return;

    // ---- load x[64]: 16 dwordx4
    float xv[NOBS];
    {
        const float4* xp = reinterpret_cast<const float4*>(x) + (size_t)t * (NOBS / 4);
        #pragma unroll
        for (int q = 0; q < NOBS / 4; ++q) {
            float4 v = xp[q];
            xv[4*q+0] = v.x; xv[4*q+1] = v.y; xv[4*q+2] = v.z; xv[4*q+3] = v.w;
        }
    }

    // ---- fc1 + relu (fully unrolled; h1 statically indexed)
    float h1[NH1];
    #pragma unroll
    for (int i = 0; i < NH1; ++i) {
        float a0 = fc1b[i], a1 = 0.f, a2 = 0.f, a3 = 0.f;
        #pragma unroll
        for (int k = 0; k < NOBS; k += 4) {
            a0 = fmaf(xv[k+0], fc1w[i*NOBS + k+0], a0);
            a1 = fmaf(xv[k+1], fc1w[i*NOBS + k+1], a1);
            a2 = fmaf(xv[k+2], fc1w[i*NOBS + k+2], a2);
            a3 = fmaf(xv[k+3], fc1w[i*NOBS + k+3], a3);
        }
        h1[i] = fmaxf((a0 + a1) + (a2 + a3), 0.f);
    }

    // ---- fc2 + relu (fully unrolled)
    float h2[NH2];
    #pragma unroll
    for (int j = 0; j < NH2; ++j) {
        float a0 = fc2b[j], a1 = 0.f;
        #pragma unroll
        for (int k = 0; k < NH1; k += 2) {
            a0 = fmaf(h1[k+0], fc2w[j*NH1 + k+0], a0);
            a1 = fmaf(h1[k+1], fc2w[j*NH1 + k+1], a1);
        }
        h2[j] = fmaxf(a0 + a1, 0.f);
    }

    // ---- load hx[50]: float2 (row is 200B -> 8B aligned)
    float hxr[NH2];
    {
        const float2* hp = reinterpret_cast<const float2*>(hx + (size_t)t * NH2);
        #pragma unroll
        for (int q = 0; q < NH2 / 2; ++q) {
            float2 v = hp[q];
            hxr[2*q+0] = v.x; hxr[2*q+1] = v.y;
        }
    }

    // ---- LSTM cell + fused fc3 accumulation
    float outa[NACT];
    #pragma unroll
    for (int a = 0; a < NACT; ++a) outa[a] = fc3b[a];

    size_t colIdx = (size_t)t;               // j*B + t, strength-reduced

    #pragma unroll 1   // keep rolled: body ~440 insts; full unroll blows I-cache
    for (int j = 0; j < NH2; ++j) {
        const float* wi = wih + (size_t)(j          ) * NH2;
        const float* wf = wih + (size_t)(NH2   + j  ) * NH2;
        const float* wg = wih + (size_t)(2*NH2 + j  ) * NH2;
        const float* wo = wih + (size_t)(3*NH2 + j  ) * NH2;
        const float* ui = whh + (size_t)(j          ) * NH2;
        const float* uf = whh + (size_t)(NH2   + j  ) * NH2;
        const float* ug = whh + (size_t)(2*NH2 + j  ) * NH2;
        const float* uo = whh + (size_t)(3*NH2 + j  ) * NH2;

        float cxv = ctile[j * 257 + tid];    // LDS, conflict-free

        float ai = bih[j]         + bhh[j];
        float af = bih[NH2 + j]   + bhh[NH2 + j];
        float ag = bih[2*NH2 + j] + bhh[2*NH2 + j];
        float ao = bih[3*NH2 + j] + bhh[3*NH2 + j];
        float bi = 0.f, bf = 0.f, bg = 0.f, bo = 0.f;  // 8 chains for ILP

        #pragma unroll
        for (int k = 0; k < NH2; ++k) {
            ai = fmaf(h2[k],  wi[k], ai);
            af = fmaf(h2[k],  wf[k], af);
            ag = fmaf(h2[k],  wg[k], ag);
            ao = fmaf(h2[k],  wo[k], ao);
            bi = fmaf(hxr[k], ui[k], bi);
            bf = fmaf(hxr[k], uf[k], bf);
            bg = fmaf(hxr[k], ug[k], bg);
            bo = fmaf(hxr[k], uo[k], bo);
        }

        float ig = fsigmoid(ai + bi);
        float fg = fsigmoid(af + bf);
        float gg = ftanh(ag + bg);
        float og = fsigmoid(ao + bo);

        float cn = fmaf(fg, cxv, ig * gg);
        float tn = ftanh(cn);
        float hn = og * tn;

        hT[colIdx] = hn;                     // coalesced (lane-stride 4B)
        cT[colIdx] = cn;                     // coalesced
        colIdx += (size_t)B;

        #pragma unroll
        for (int a = 0; a < NACT; ++a)
            outa[a] = fmaf(hn, fc3w[a*NH2 + j], outa[a]);
    }

    // ---- out = tanh(fc3), vectorized store
    {
        float4* op = reinterpret_cast<float4*>(outp + (size_t)t * NACT);
        #pragma unroll
        for (int q = 0; q < NACT / 4; ++q) {
            float4 v;
            v.x = ftanh(outa[4*q+0]);
            v.y = ftanh(outa[4*q+1]);
            v.z = ftanh(outa[4*q+2]);
            v.w = ftanh(outa[4*q+3]);
            op[q] = v;
        }
    }
}

// ---------------------------------------------------------------------------
// Fallback (ws too small): direct kernel, scattered row I/O (round-1 version).
// ---------------------------------------------------------------------------
__global__ __launch_bounds__(256) void actor_kernel_direct(
    const float* __restrict__ x,
    const float* __restrict__ hx,
    const float* __restrict__ cx,
    const float* __restrict__ fc1w, const float* __restrict__ fc1b,
    const float* __restrict__ fc2w, const float* __restrict__ fc2b,
    const float* __restrict__ wih,  const float* __restrict__ whh,
    const float* __restrict__ bih,  const float* __restrict__ bhh,
    const float* __restrict__ fc3w, const float* __restrict__ fc3b,
    float* __restrict__ outp, float* __restrict__ hxo, float* __restrict__ cxo,
    int B)
{
    const int t = blockIdx.x * blockDim.x + threadIdx.x;
    if (t >= B) return;
    float xv[NOBS];
    {
        const float4* xp = reinterpret_cast<const float4*>(x) + (size_t)t * (NOBS / 4);
        #pragma unroll
        for (int q = 0; q < NOBS / 4; ++q) {
            float4 v = xp[q];
            xv[4*q+0] = v.x; xv[4*q+1] = v.y; xv[4*q+2] = v.z; xv[4*q+3] = v.w;
        }
    }
    float h1[NH1];
    #pragma unroll
    for (int i = 0; i < NH1; ++i) {
        float a0 = fc1b[i], a1 = 0.f, a2 = 0.f, a3 = 0.f;
        #pragma unroll
        for (int k = 0; k < NOBS; k += 4) {
            a0 = fmaf(xv[k+0], fc1w[i*NOBS + k+0], a0);
            a1 = fmaf(xv[k+1], fc1w[i*NOBS + k+1], a1);
            a2 = fmaf(xv[k+2], fc1w[i*NOBS + k+2], a2);
            a3 = fmaf(xv[k+3], fc1w[i*NOBS + k+3], a3);
        }
        h1[i] = fmaxf((a0 + a1) + (a2 + a3), 0.f);
    }
    float h2[NH2];
    #pragma unroll
    for (int j = 0; j < NH2; ++j) {
        float a0 = fc2b[j], a1 = 0.f;
        #pragma unroll
        for (int k = 0; k < NH1; k += 2) {
            a0 = fmaf(h1[k+0], fc2w[j*NH1 + k+0], a0);
            a1 = fmaf(h1[k+1], fc2w[j*NH1 + k+1], a1);
        }
        h2[j] = fmaxf(a0 + a1, 0.f);
    }
    float hxr[NH2];
    {
        const float2* hp = reinterpret_cast<const float2*>(hx + (size_t)t * NH2);
        #pragma unroll
        for (int q = 0; q < NH2 / 2; ++q) {
            float2 v = hp[q];
            hxr[2*q+0] = v.x; hxr[2*q+1] = v.y;
        }
    }
    float outa[NACT];
    #pragma unroll
    for (int a = 0; a < NACT; ++a) outa[a] = fc3b[a];
    const float* cxrow = cx  + (size_t)t * NH2;
    float* hxorow      = hxo + (size_t)t * NH2;
    float* cxorow      = cxo + (size_t)t * NH2;
    #pragma unroll 1
    for (int j = 0; j < NH2; ++j) {
        const float* wi = wih + (size_t)(j          ) * NH2;
        const float* wf = wih + (size_t)(NH2   + j  ) * NH2;
        const float* wg = wih + (size_t)(2*NH2 + j  ) * NH2;
        const float* wo = wih + (size_t)(3*NH2 + j  ) * NH2;
        const float* ui = whh + (size_t)(j          ) * NH2;
        const float* uf = whh + (size_t)(NH2   + j  ) * NH2;
        const float* ug = whh + (size_t)(2*NH2 + j  ) * NH2;
        const float* uo = whh + (size_t)(3*NH2 + j  ) * NH2;
        float ai = bih[j]         + bhh[j];
        float af = bih[NH2 + j]   + bhh[NH2 + j];
        float ag = bih[2*NH2 + j] + bhh[2*NH2 + j];
        float ao = bih[3*NH2 + j] + bhh[3*NH2 + j];
        float bi = 0.f, bf = 0.f, bg = 0.f, bo = 0.f;
        #pragma unroll
        for (int k = 0; k < NH2; ++k) {
            ai = fmaf(h2[k],  wi[k], ai);
            af = fmaf(h2[k],  wf[k], af);
            ag = fmaf(h2[k],  wg[k], ag);
            ao = fmaf(h2[k],  wo[k], ao);
            bi = fmaf(hxr[k], ui[k], bi);
            bf = fmaf(hxr[k], uf[k], bf);
            bg = fmaf(hxr[k], ug[k], bg);
            bo = fmaf(hxr[k], uo[k], bo);
        }
        float ig = fsigmoid(ai + bi);
        float fg = fsigmoid(af + bf);
        float gg = ftanh(ag + bg);
        float og = fsigmoid(ao + bo);
        float cn = fmaf(fg, cxrow[j], ig * gg);
        float hn = og * ftanh(cn);
        cxorow[j] = cn;
        hxorow[j] = hn;
        #pragma unroll
        for (int a = 0; a < NACT; ++a)
            outa[a] = fmaf(hn, fc3w[a*NH2 + j], outa[a]);
    }
    {
        float4* op = reinterpret_cast<float4*>(outp + (size_t)t * NACT);
        #pragma unroll
        for (int q = 0; q < NACT / 4; ++q) {
            float4 v;
            v.x = ftanh(outa[4*q+0]);
            v.y = ftanh(outa[4*q+1]);
            v.z = ftanh(outa[4*q+2]);
            v.w = ftanh(outa[4*q+3]);
            op[q] = v;
        }
    }
}

extern "C" void kernel_launch(void* const* d_in, const int* in_sizes, int n_in,
                              void* d_out, int out_size, void* d_ws, size_t ws_size,
                              hipStream_t stream) {
    const float* x    = (const float*)d_in[0];
    const float* hx   = (const float*)d_in[1];
    const float* cx   = (const float*)d_in[2];
    const float* fc1w = (const float*)d_in[3];
    const float* fc1b = (const float*)d_in[4];
    const float* fc2w = (const float*)d_in[5];
    const float* fc2b = (const float*)d_in[6];
    const float* wih  = (const float*)d_in[7];
    const float* whh  = (const float*)d_in[8];
    const float* bih  = (const float*)d_in[9];
    const float* bhh  = (const float*)d_in[10];
    const float* fc3w = (const float*)d_in[11];
    const float* fc3b = (const float*)d_in[12];

    const int B = in_sizes[0] / NOBS;   // 524288

    float* outp = (float*)d_out;
    float* hxo  = outp + (size_t)B * NACT;
    float* cxo  = hxo  + (size_t)B * NH2;

    const size_t arr = (size_t)B * NH2;            // elements per [50][B] array
    const int block  = 256;
    const int grid   = (B + block - 1) / block;

    if (ws_size >= 2 * arr * sizeof(float)) {
        float* hT = (float*)d_ws;                  // hn, [50][B]
        float* cT = hT + arr;                      // cn, [50][B]

        hipLaunchKernelGGL(actor_kernel, dim3(grid), dim3(block), 0, stream,
                           x, hx, cx, fc1w, fc1b, fc2w, fc2b,
                           wih, whh, bih, bhh, fc3w, fc3b,
                           outp, hT, cT, B);
        hipLaunchKernelGGL(transpose_out, dim3(grid, 2), dim3(block), 0, stream,
                           hT, hxo, cT, cxo, B);
    } else {
        hipLaunchKernelGGL(actor_kernel_direct, dim3(grid), dim3(block), 0, stream,
                           x, hx, cx, fc1w, fc1b, fc2w, fc2b,
                           wih, whh, bih, bhh, fc3w, fc3b,
                           outp, hxo, cxo, B);
    }
}